// Round 3
// baseline (510.005 us; speedup 1.0000x reference)
//
#include <hip/hip_runtime.h>
#include <cstdint>
#include <cstddef>
#include <cmath>

#define B_  4
#define H_  16
#define NT  512
#define NL  512
#define E_  64
#define P_  1024
#define HE  1024
#define BH  64

typedef __attribute__((ext_vector_type(8))) short short8;
typedef __attribute__((ext_vector_type(4))) float f32x4;
typedef unsigned short u16;

#define MFMA(a, b, c) __builtin_amdgcn_mfma_f32_16x16x32_bf16(a, b, c, 0, 0, 0)

static __device__ inline u16 f2bf_rne(float f) {
  unsigned u = __float_as_uint(f);
  unsigned r = u + 0x7FFFu + ((u >> 16) & 1u);
  return (u16)(r >> 16);
}

// async 16B global -> LDS (wave-uniform LDS base + lane*16)
static __device__ inline void gl_lds16(const void* g, void* l) {
  __builtin_amdgcn_global_load_lds(
      (const __attribute__((address_space(1))) void*)g,
      (__attribute__((address_space(3))) void*)l, 16, 0, 0);
}

// ---------------------------------------------------------------------------
// Kernel A: per (b,n):
//   inv = 1/(exp(logvar)+8); mobv hi/lo bf16 split;
//   ibvT[b][p][n] = bf16(inv)  (transposed for MFMA B-fragments);
//   bias = log(pi) - 0.5*sum(mu^2*inv) - 0.5*sum(log(bv))
// ---------------------------------------------------------------------------
__global__ __launch_bounds__(256) void k_precompute(
    const float* __restrict__ mu, const float* __restrict__ logvar,
    const float* __restrict__ pi, u16* __restrict__ mobv_hi,
    u16* __restrict__ mobv_lo, u16* __restrict__ ibvT,
    float* __restrict__ bias) {
  const int bn = blockIdx.x;          // 0 .. B_*NL-1
  const int b = bn >> 9, n = bn & 511;
  const int t = threadIdx.x;
  const size_t base = (size_t)bn * P_;
  float t2 = 0.f, t3 = 0.f;
#pragma unroll
  for (int i = 0; i < P_ / 256; ++i) {
    const int p = t + i * 256;
    const float lv  = logvar[base + p];
    const float v   = expf(lv);
    const float bv  = v + 8.0f;
    const float inv = 1.0f / bv;
    const float m   = mu[base + p];
    const float x   = m * inv;
    const unsigned bits = __float_as_uint(x);
    mobv_hi[base + p] = (u16)(bits >> 16);
    const float r = x - __uint_as_float(bits & 0xFFFF0000u);
    mobv_lo[base + p] = (u16)(__float_as_uint(r) >> 16);
    ibvT[((size_t)b * P_ + p) * NL + n] = f2bf_rne(inv);
    t2 += m * x;
    t3 += logf(bv);
  }
  __shared__ float r2[256];
  __shared__ float r3[256];
  r2[t] = t2; r3[t] = t3;
  __syncthreads();
  for (int s = 128; s > 0; s >>= 1) {
    if (t < s) { r2[t] += r2[t + s]; r3[t] += r3[t + s]; }
    __syncthreads();
  }
  if (t == 0) {
    const float pv = pi[bn];
    float bb;
    if (pv <= 0.f) bb = -INFINITY;
    else bb = logf(fmaxf(pv, 1.17549435e-38f)) - 0.5f * r2[0] - 0.5f * r3[0];
    bias[bn] = bb;
  }
}

// ---------------------------------------------------------------------------
// wv fp32 -> bf16 copy
// ---------------------------------------------------------------------------
__global__ __launch_bounds__(256) void k_wvcast(const float* __restrict__ wv,
                                                u16* __restrict__ wvb) {
  const int i = (blockIdx.x * 256 + threadIdx.x) * 4;
  const float4 f = *(const float4*)&wv[i];
  wvb[i + 0] = f2bf_rne(f.x);
  wvb[i + 1] = f2bf_rne(f.y);
  wvb[i + 2] = f2bf_rne(f.z);
  wvb[i + 3] = f2bf_rne(f.w);
}

// ---------------------------------------------------------------------------
// Kernel W (MFMA): W2pT[b][he][n] = bf16(8*sum_p mobv[n][p]*wv[he][p] + bv[he][n])
// M=512(n) x N=1024(he) x K=1024. Tile 64x128xBK32; 4 waves 2x2 (wave 32x64).
// ---------------------------------------------------------------------------
__global__ __launch_bounds__(256) void k_w2p(
    const u16* __restrict__ mobv_hi, const u16* __restrict__ mobv_lo,
    const u16* __restrict__ wvb, const float* __restrict__ bv_,
    u16* __restrict__ W2pT) {
  const int b    = blockIdx.z;
  const int row0 = blockIdx.x * 64;    // n
  const int col0 = blockIdx.y * 128;   // he
  const int t = threadIdx.x;
  const int wave = t >> 6, lane = t & 63;
  const int l16 = lane & 15, sel = lane >> 4;
  const int mrow = (wave >> 1) * 32, ncol = (wave & 1) * 64;

  __shared__ u16 Ah[64 * 32];    // 4KB
  __shared__ u16 Al[64 * 32];    // 4KB
  __shared__ u16 Bs[128 * 32];   // 8KB

  const u16* Abh = mobv_hi + ((size_t)b * NL + row0) * P_;
  const u16* Abl = mobv_lo + ((size_t)b * NL + row0) * P_;
  const u16* Bb  = wvb + (size_t)col0 * P_;

  f32x4 acc[2][4];
#pragma unroll
  for (int i = 0; i < 2; ++i)
#pragma unroll
    for (int j = 0; j < 4; ++j) acc[i][j] = (f32x4){0.f, 0.f, 0.f, 0.f};

  for (int k0 = 0; k0 < P_; k0 += 32) {
    {  // A tiles: 256 chunks each
      const int c = t;
      const int row = c >> 2, k8 = (c & 3) ^ ((row >> 1) & 3);
      gl_lds16(Abh + (size_t)row * P_ + k0 + k8 * 8, &Ah[wave * 64 * 8]);
      gl_lds16(Abl + (size_t)row * P_ + k0 + k8 * 8, &Al[wave * 64 * 8]);
    }
#pragma unroll
    for (int i = 0; i < 2; ++i) {  // B tile: 512 chunks
      const int c = t + i * 256;
      const int row = c >> 2, k8 = (c & 3) ^ ((row >> 1) & 3);
      gl_lds16(Bb + (size_t)row * P_ + k0 + k8 * 8,
               &Bs[(i * 256 + wave * 64) * 8]);
    }
    __syncthreads();
    short8 ah[2], al[2], bf[4];
#pragma unroll
    for (int mt = 0; mt < 2; ++mt) {
      const int r = mrow + mt * 16 + l16;
      const int ch = sel ^ ((r >> 1) & 3);
      ah[mt] = *(const short8*)&Ah[r * 32 + ch * 8];
      al[mt] = *(const short8*)&Al[r * 32 + ch * 8];
    }
#pragma unroll
    for (int nt = 0; nt < 4; ++nt) {
      const int r = ncol + nt * 16 + l16;
      const int ch = sel ^ ((r >> 1) & 3);
      bf[nt] = *(const short8*)&Bs[r * 32 + ch * 8];
    }
#pragma unroll
    for (int mt = 0; mt < 2; ++mt)
#pragma unroll
      for (int nt = 0; nt < 4; ++nt) {
        acc[mt][nt] = MFMA(ah[mt], bf[nt], acc[mt][nt]);
        acc[mt][nt] = MFMA(al[mt], bf[nt], acc[mt][nt]);
      }
    __syncthreads();
  }
#pragma unroll
  for (int mt = 0; mt < 2; ++mt) {
    const int nbase = row0 + mrow + mt * 16 + sel * 4;
#pragma unroll
    for (int nt = 0; nt < 4; ++nt) {
      const int he = col0 + ncol + nt * 16 + l16;
      const float4 bvv = *(const float4*)&bv_[(size_t)he * NL + nbase];
      ushort4 o;
      o.x = f2bf_rne(8.0f * acc[mt][nt][0] + bvv.x);
      o.y = f2bf_rne(8.0f * acc[mt][nt][1] + bvv.y);
      o.z = f2bf_rne(8.0f * acc[mt][nt][2] + bvv.z);
      o.w = f2bf_rne(8.0f * acc[mt][nt][3] + bvv.w);
      *(ushort4*)&W2pT[((size_t)b * HE + he) * NL + nbase] = o;
    }
  }
}

// ---------------------------------------------------------------------------
// Kernel S (MFMA): scores = U @ mobv^T, 3-term split-bf16. 128x128xBK32.
// Round-1 structure (all-async gl_lds staging, per-wave in-register split)
// + T3-minimum double-buffer pipeline: issue K-step k+1 staging at the top
// of iteration k, compute k from the resident buffer, ONE barrier per step.
// The end-of-step vmcnt drain now waits on loads covered by a full compute
// phase instead of freshly-issued ones.
// ---------------------------------------------------------------------------
__global__ __launch_bounds__(256) void k_scores(
    const float* __restrict__ U, const u16* __restrict__ mobv_hi,
    const u16* __restrict__ mobv_lo, const float* __restrict__ pb,
    const float* __restrict__ bias, const uint8_t* __restrict__ mask,
    float* __restrict__ attn) {
  const int b    = blockIdx.z;
  const int row0 = blockIdx.x * 128;  // gr within b
  const int col0 = blockIdx.y * 128;  // n
  const int t = threadIdx.x;
  const int wave = t >> 6, lane = t & 63;
  const int l16 = lane & 15, sel = lane >> 4;
  const int mrow = (wave >> 1) * 64, ncol = (wave & 1) * 64;

  __shared__ float Af[2][128 * 32];  // 32KB
  __shared__ u16   Bh[2][128 * 32];  // 16KB
  __shared__ u16   Bl[2][128 * 32];  // 16KB

  const float* Ab  = U + ((size_t)b * 8192 + row0) * P_;
  const u16*   Bbh = mobv_hi + ((size_t)b * NL + col0) * P_;
  const u16*   Bbl = mobv_lo + ((size_t)b * NL + col0) * P_;

  f32x4 acc[4][4];
#pragma unroll
  for (int i = 0; i < 4; ++i)
#pragma unroll
    for (int j = 0; j < 4; ++j) acc[i][j] = (f32x4){0.f, 0.f, 0.f, 0.f};

  auto stage = [&](int buf, int k0) {
    // A fp32: 1024 chunks of 16B
#pragma unroll
    for (int i = 0; i < 4; ++i) {
      const int c = t + i * 256;
      const int row = c >> 3, k4 = (c & 7) ^ (row & 7);
      gl_lds16(Ab + (size_t)row * P_ + k0 + k4 * 4,
               &Af[buf][(i * 256 + wave * 64) * 4]);
    }
    // B hi/lo bf16: 512 chunks each
#pragma unroll
    for (int i = 0; i < 2; ++i) {
      const int c = t + i * 256;
      const int row = c >> 2, k8 = (c & 3) ^ ((row >> 1) & 3);
      gl_lds16(Bbh + (size_t)row * P_ + k0 + k8 * 8,
               &Bh[buf][(i * 256 + wave * 64) * 8]);
      gl_lds16(Bbl + (size_t)row * P_ + k0 + k8 * 8,
               &Bl[buf][(i * 256 + wave * 64) * 8]);
    }
  };

  stage(0, 0);
  __syncthreads();
  int cur = 0;
  for (int k0 = 0; k0 < P_; k0 += 32) {
    if (k0 + 32 < P_) stage(cur ^ 1, k0 + 32);

    short8 ah[4], al[4], bh[4], bl[4];
#pragma unroll
    for (int mt = 0; mt < 4; ++mt) {
      const int r = mrow + mt * 16 + l16;
      const int c0 = (sel * 2) ^ (r & 7);
      const int c1 = (sel * 2 + 1) ^ (r & 7);
      const float4 f0 = *(const float4*)&Af[cur][r * 32 + c0 * 4];
      const float4 f1 = *(const float4*)&Af[cur][r * 32 + c1 * 4];
      const float fv[8] = {f0.x, f0.y, f0.z, f0.w, f1.x, f1.y, f1.z, f1.w};
#pragma unroll
      for (int j = 0; j < 8; ++j) {
        const unsigned bits = __float_as_uint(fv[j]);
        ah[mt][j] = (short)(bits >> 16);
        const float rr = fv[j] - __uint_as_float(bits & 0xFFFF0000u);
        al[mt][j] = (short)(__float_as_uint(rr) >> 16);
      }
    }
#pragma unroll
    for (int nt = 0; nt < 4; ++nt) {
      const int r = ncol + nt * 16 + l16;
      const int ch = sel ^ ((r >> 1) & 3);
      bh[nt] = *(const short8*)&Bh[cur][r * 32 + ch * 8];
      bl[nt] = *(const short8*)&Bl[cur][r * 32 + ch * 8];
    }
#pragma unroll
    for (int mt = 0; mt < 4; ++mt)
#pragma unroll
      for (int nt = 0; nt < 4; ++nt) {
        acc[mt][nt] = MFMA(ah[mt], bh[nt], acc[mt][nt]);
        acc[mt][nt] = MFMA(ah[mt], bl[nt], acc[mt][nt]);
        acc[mt][nt] = MFMA(al[mt], bh[nt], acc[mt][nt]);
      }
    __syncthreads();
    cur ^= 1;
  }

  const int bh_ = b * H_ + (row0 >> 9);
  float pbv[4][4];
#pragma unroll
  for (int mt = 0; mt < 4; ++mt)
#pragma unroll
    for (int r = 0; r < 4; ++r)
      pbv[mt][r] = pb[(size_t)b * 8192 + row0 + mrow + mt * 16 + sel * 4 + r];
#pragma unroll
  for (int nt = 0; nt < 4; ++nt) {
    const int n = col0 + ncol + nt * 16 + l16;
    const float bcol = bias[b * NL + n];
    const bool mk = mask[(size_t)bh_ * NL + n] != 0;
#pragma unroll
    for (int mt = 0; mt < 4; ++mt) {
#pragma unroll
      for (int r = 0; r < 4; ++r) {
        const int row = row0 + mrow + mt * 16 + sel * 4 + r;
        float s = acc[mt][nt][r] + pbv[mt][r] + bcol;
        if (mk) s = -INFINITY;
        attn[((size_t)b * 8192 + row) * NL + n] = s;
      }
    }
  }
}

// ---------------------------------------------------------------------------
// Kernel SM: softmax over last dim (512), wave-per-row, barrier-free.
// Also emits bf16 copy.
// ---------------------------------------------------------------------------
__global__ __launch_bounds__(256) void k_softmax(float* __restrict__ attn,
                                                 u16* __restrict__ attn_bf) {
  const int t = threadIdx.x;
  const int wave = t >> 6, lane = t & 63;
  const size_t r = (size_t)blockIdx.x * 4 + wave;
  float* row = attn + r * NL;
  const float4 v0 = ((const float4*)row)[lane * 2];
  const float4 v1 = ((const float4*)row)[lane * 2 + 1];
  float m = fmaxf(fmaxf(fmaxf(v0.x, v0.y), fmaxf(v0.z, v0.w)),
                  fmaxf(fmaxf(v1.x, v1.y), fmaxf(v1.z, v1.w)));
#pragma unroll
  for (int off = 32; off > 0; off >>= 1) m = fmaxf(m, __shfl_xor(m, off, 64));
  float e[8];
  e[0] = expf(v0.x - m); e[1] = expf(v0.y - m);
  e[2] = expf(v0.z - m); e[3] = expf(v0.w - m);
  e[4] = expf(v1.x - m); e[5] = expf(v1.y - m);
  e[6] = expf(v1.z - m); e[7] = expf(v1.w - m);
  float s = ((e[0] + e[1]) + (e[2] + e[3])) + ((e[4] + e[5]) + (e[6] + e[7]));
#pragma unroll
  for (int off = 32; off > 0; off >>= 1) s += __shfl_xor(s, off, 64);
  const float inv = 1.0f / s;
  float4 o0, o1;
  o0.x = e[0] * inv; o0.y = e[1] * inv; o0.z = e[2] * inv; o0.w = e[3] * inv;
  o1.x = e[4] * inv; o1.y = e[5] * inv; o1.z = e[6] * inv; o1.w = e[7] * inv;
  ((float4*)row)[lane * 2] = o0;
  ((float4*)row)[lane * 2 + 1] = o1;
  ushort4 b0, b1;
  b0.x = f2bf_rne(o0.x); b0.y = f2bf_rne(o0.y);
  b0.z = f2bf_rne(o0.z); b0.w = f2bf_rne(o0.w);
  b1.x = f2bf_rne(o1.x); b1.y = f2bf_rne(o1.y);
  b1.z = f2bf_rne(o1.z); b1.w = f2bf_rne(o1.w);
  ((ushort4*)(attn_bf + r * NL))[lane * 2] = b0;
  ((ushort4*)(attn_bf + r * NL))[lane * 2 + 1] = b1;
}

// ---------------------------------------------------------------------------
// Kernel M (MFMA): opS[m][p] = bf16((1 - 8*s[m][p]) * U[m][p]),
//   s = attn_bf @ ibvT   (M=8192/b x N=1024(p) x K=512(n)).
// Tile 128x128xBK32; 4 waves 2x2 (wave 64x64). Double-buffered (T3-minimum).
// ---------------------------------------------------------------------------
__global__ __launch_bounds__(256) void k_mid(
    const u16* __restrict__ attn_bf, const u16* __restrict__ ibvT,
    const float* __restrict__ U, u16* __restrict__ opS) {
  const int b    = blockIdx.z;
  const int row0 = blockIdx.x * 128;  // m within b
  const int col0 = blockIdx.y * 128;  // p
  const int t = threadIdx.x;
  const int wave = t >> 6, lane = t & 63;
  const int l16 = lane & 15, sel = lane >> 4;
  const int mrow = (wave >> 1) * 64, ncol = (wave & 1) * 64;

  __shared__ u16 As[2][128 * 32];  // 16KB
  __shared__ u16 Bs[2][128 * 32];  // 16KB

  const u16* Ab = attn_bf + ((size_t)b * 8192 + row0) * NL;
  const u16* Bb = ibvT + ((size_t)b * P_ + col0) * NL;

  f32x4 acc[4][4];
#pragma unroll
  for (int i = 0; i < 4; ++i)
#pragma unroll
    for (int j = 0; j < 4; ++j) acc[i][j] = (f32x4){0.f, 0.f, 0.f, 0.f};

  auto stage = [&](int buf, int k0) {
#pragma unroll
    for (int i = 0; i < 2; ++i) {  // 512 chunks each for A and B
      const int c = t + i * 256;
      const int row = c >> 2, k8 = (c & 3) ^ ((row >> 1) & 3);
      gl_lds16(Ab + (size_t)row * NL + k0 + k8 * 8,
               &As[buf][(i * 256 + wave * 64) * 8]);
      gl_lds16(Bb + (size_t)row * NL + k0 + k8 * 8,
               &Bs[buf][(i * 256 + wave * 64) * 8]);
    }
  };

  stage(0, 0);
  __syncthreads();
  int cur = 0;
  for (int k0 = 0; k0 < NL; k0 += 32) {
    if (k0 + 32 < NL) stage(cur ^ 1, k0 + 32);
    short8 af[4], bf[4];
#pragma unroll
    for (int mt = 0; mt < 4; ++mt) {
      const int r = mrow + mt * 16 + l16;
      const int ch = sel ^ ((r >> 1) & 3);
      af[mt] = *(const short8*)&As[cur][r * 32 + ch * 8];
    }
#pragma unroll
    for (int nt = 0; nt < 4; ++nt) {
      const int r = ncol + nt * 16 + l16;
      const int ch = sel ^ ((r >> 1) & 3);
      bf[nt] = *(const short8*)&Bs[cur][r * 32 + ch * 8];
    }
#pragma unroll
    for (int mt = 0; mt < 4; ++mt)
#pragma unroll
      for (int nt = 0; nt < 4; ++nt)
        acc[mt][nt] = MFMA(af[mt], bf[nt], acc[mt][nt]);
    __syncthreads();
    cur ^= 1;
  }

#pragma unroll
  for (int mt = 0; mt < 4; ++mt) {
#pragma unroll
    for (int r = 0; r < 4; ++r) {
      const int m = row0 + mrow + mt * 16 + sel * 4 + r;
      const float* Urow = U + ((size_t)b * 8192 + m) * P_;
      u16* orow = opS + ((size_t)b * 8192 + m) * P_;
#pragma unroll
      for (int nt = 0; nt < 4; ++nt) {
        const int p = col0 + ncol + nt * 16 + l16;
        const float u = Urow[p];
        orow[p] = f2bf_rne((1.0f - 8.0f * acc[mt][nt][r]) * u);
      }
    }
  }
}

// ---------------------------------------------------------------------------
// Kernel O2 (MFMA): out[m][e] = opS[m][:] @ wvb[he][:] + attn_bf[m][:] @ W2pT[he][:]
// Per block: 64 rows x 64 e for one bh. Tile 64x64xBK64, 4 waves 2x2 (32x32).
// ---------------------------------------------------------------------------
__global__ __launch_bounds__(256) void k_out2(
    const u16* __restrict__ opS, const u16* __restrict__ attn_bf,
    const u16* __restrict__ wvb, const u16* __restrict__ W2pT,
    float* __restrict__ out) {
  const int bh = blockIdx.y;
  const int b = bh >> 4, h = bh & 15;
  const int row0g = bh * NT + blockIdx.x * 64;  // global row in [B*H*Nt)
  const int t = threadIdx.x;
  const int wave = t >> 6, lane = t & 63;
  const int l16 = lane & 15, sel = lane >> 4;
  const int mrow = (wave >> 1) * 32, ncol = (wave & 1) * 32;

  __shared__ u16 As[64 * 64];  // 8KB
  __shared__ u16 Bs[64 * 64];  // 8KB

  f32x4 acc[2][2];
#pragma unroll
  for (int i = 0; i < 2; ++i)
#pragma unroll
    for (int j = 0; j < 2; ++j) acc[i][j] = (f32x4){0.f, 0.f, 0.f, 0.f};

  // ---- term 1: opS @ wvb^T  (K = p, 1024) ----
  const u16* Ab1 = opS + (size_t)row0g * P_;
  const u16* Bb1 = wvb + (size_t)(h * 64) * P_;
  for (int k0 = 0; k0 < P_; k0 += 64) {
#pragma unroll
    for (int i = 0; i < 2; ++i) {  // 512 chunks each
      const int c = t + i * 256;
      const int row = c >> 3, k8 = (c & 7) ^ (row & 7);
      gl_lds16(Ab1 + (size_t)row * P_ + k0 + k8 * 8,
               &As[(i * 256 + wave * 64) * 8]);
      gl_lds16(Bb1 + (size_t)row * P_ + k0 + k8 * 8,
               &Bs[(i * 256 + wave * 64) * 8]);
    }
    __syncthreads();
    short8 af[2][2], bf[2][2];
#pragma unroll
    for (int mt = 0; mt < 2; ++mt) {
      const int r = mrow + mt * 16 + l16;
#pragma unroll
      for (int kk = 0; kk < 2; ++kk) {
        const int ch = (kk * 4 + sel) ^ (r & 7);
        af[mt][kk] = *(const short8*)&As[r * 64 + ch * 8];
      }
    }
#pragma unroll
    for (int nt = 0; nt < 2; ++nt) {
      const int r = ncol + nt * 16 + l16;
#pragma unroll
      for (int kk = 0; kk < 2; ++kk) {
        const int ch = (kk * 4 + sel) ^ (r & 7);
        bf[nt][kk] = *(const short8*)&Bs[r * 64 + ch * 8];
      }
    }
#pragma unroll
    for (int mt = 0; mt < 2; ++mt)
#pragma unroll
      for (int nt = 0; nt < 2; ++nt) {
        acc[mt][nt] = MFMA(af[mt][0], bf[nt][0], acc[mt][nt]);
        acc[mt][nt] = MFMA(af[mt][1], bf[nt][1], acc[mt][nt]);
      }
    __syncthreads();
  }

  // ---- term 2: attn_bf @ W2pT^T  (K = n, 512) ----
  const u16* Ab2 = attn_bf + (size_t)row0g * NL;
  const u16* Bb2 = W2pT + ((size_t)b * HE + h * 64) * NL;
  for (int k0 = 0; k0 < NL; k0 += 64) {
#pragma unroll
    for (int i = 0; i < 2; ++i) {
      const int c = t + i * 256;
      const int row = c >> 3, k8 = (c & 7) ^ (row & 7);
      gl_lds16(Ab2 + (size_t)row * NL + k0 + k8 * 8,
               &As[(i * 256 + wave * 64) * 8]);
      gl_lds16(Bb2 + (size_t)row * NL + k0 + k8 * 8,
               &Bs[(i * 256 + wave * 64) * 8]);
    }
    __syncthreads();
    short8 af[2][2], bf[2][2];
#pragma unroll
    for (int mt = 0; mt < 2; ++mt) {
      const int r = mrow + mt * 16 + l16;
#pragma unroll
      for (int kk = 0; kk < 2; ++kk) {
        const int ch = (kk * 4 + sel) ^ (r & 7);
        af[mt][kk] = *(const short8*)&As[r * 64 + ch * 8];
      }
    }
#pragma unroll
    for (int nt = 0; nt < 2; ++nt) {
      const int r = ncol + nt * 16 + l16;
#pragma unroll
      for (int kk = 0; kk < 2; ++kk) {
        const int ch = (kk * 4 + sel) ^ (r & 7);
        bf[nt][kk] = *(const short8*)&Bs[r * 64 + ch * 8];
      }
    }
#pragma unroll
    for (int mt = 0; mt < 2; ++mt)
#pragma unroll
      for (int nt = 0; nt < 2; ++nt) {
        acc[mt][nt] = MFMA(af[mt][0], bf[nt][0], acc[mt][nt]);
        acc[mt][nt] = MFMA(af[mt][1], bf[nt][1], acc[mt][nt]);
      }
    __syncthreads();
  }

#pragma unroll
  for (int mt = 0; mt < 2; ++mt)
#pragma unroll
    for (int nt = 0; nt < 2; ++nt)
#pragma unroll
      for (int r = 0; r < 4; ++r) {
        const int row = row0g + mrow + mt * 16 + sel * 4 + r;
        const int e = ncol + nt * 16 + l16;
        out[(size_t)row * E_ + e] = acc[mt][nt][r];
      }
}

// ---------------------------------------------------------------------------
extern "C" void kernel_launch(void* const* d_in, const int* in_sizes, int n_in,
                              void* d_out, int out_size, void* d_ws, size_t ws_size,
                              hipStream_t stream) {
  const float*   u    = (const float*)d_in[0];   // [B,H,Nt,P]
  const float*   pb   = (const float*)d_in[1];   // [B,H,Nt,1]
  const float*   mu   = (const float*)d_in[2];   // [B,Nl,P]
  const float*   logv = (const float*)d_in[3];   // [B,Nl,P]
  const float*   pi   = (const float*)d_in[4];   // [B,Nl,1]
  const float*   wv   = (const float*)d_in[5];   // [H,E,P]
  const float*   bv   = (const float*)d_in[6];   // [H,E,Nl]
  const uint8_t* mask = (const uint8_t*)d_in[7]; // [B*H,1,Nl] bool

  float* out  = (float*)d_out;                      // [B*H,Nt,E]
  float* attn = out + (size_t)BH * NT * E_;         // [B*H,Nt,Nl]

  u16*   mobv_hi = (u16*)d_ws;                              // 4 MB
  u16*   mobv_lo = mobv_hi + (size_t)B_ * NL * P_;          // 4 MB
  u16*   ibvT    = mobv_lo + (size_t)B_ * NL * P_;          // [b][p][n] 4 MB
  u16*   W2pT    = ibvT + (size_t)B_ * P_ * NL;             // [b][he][n] 4 MB
  u16*   wvb     = W2pT + (size_t)B_ * HE * NL;             // [he][p] 2 MB
  float* bias    = (float*)(wvb + (size_t)HE * P_);         // B*NL fp32 (8 KB)
  u16*   attn_bf = (u16*)(bias + (size_t)B_ * NL);          // [B*H,Nt,Nl] 32 MB
  u16*   opS     = attn_bf + (size_t)BH * NT * NL;          // [B*H,Nt,P] 64 MB

  k_precompute<<<B_ * NL, 256, 0, stream>>>(mu, logv, pi, mobv_hi, mobv_lo,
                                            ibvT, bias);
  k_wvcast<<<(HE * P_) / 1024, 256, 0, stream>>>(wv, wvb);
  k_w2p<<<dim3(NL / 64, HE / 128, B_), 256, 0, stream>>>(mobv_hi, mobv_lo, wvb,
                                                         bv, W2pT);
  k_scores<<<dim3(8192 / 128, NL / 128, B_), 256, 0, stream>>>(
      u, mobv_hi, mobv_lo, pb, bias, mask, attn);
  k_softmax<<<(B_ * H_ * NT) / 4, 256, 0, stream>>>(attn, attn_bf);
  k_mid<<<dim3(8192 / 128, P_ / 128, B_), 256, 0, stream>>>(attn_bf, ibvT, u,
                                                            opS);
  k_out2<<<dim3(NT / 64, BH), 256, 0, stream>>>(opS, attn_bf, wvb, W2pT, out);
}

// Round 4
// 464.915 us; speedup vs baseline: 1.0970x; 1.0970x over previous
//
#include <hip/hip_runtime.h>
#include <cstdint>
#include <cstddef>
#include <cmath>

#define B_  4
#define H_  16
#define NT  512
#define NL  512
#define E_  64
#define P_  1024
#define HE  1024
#define BH  64

typedef __attribute__((ext_vector_type(8))) short short8;
typedef __attribute__((ext_vector_type(8))) unsigned short ushort8;
typedef __attribute__((ext_vector_type(4))) float f32x4;
typedef unsigned short u16;

#define MFMA(a, b, c) __builtin_amdgcn_mfma_f32_16x16x32_bf16(a, b, c, 0, 0, 0)

static __device__ inline u16 f2bf_rne(float f) {
  unsigned u = __float_as_uint(f);
  unsigned r = u + 0x7FFFu + ((u >> 16) & 1u);
  return (u16)(r >> 16);
}

// async 16B global -> LDS (wave-uniform LDS base + lane*16)
static __device__ inline void gl_lds16(const void* g, void* l) {
  __builtin_amdgcn_global_load_lds(
      (const __attribute__((address_space(1))) void*)g,
      (__attribute__((address_space(3))) void*)l, 16, 0, 0);
}

// ---------------------------------------------------------------------------
// Kernel A: per (b,n):
//   inv = 1/(exp(logvar)+8); mobv hi/lo bf16 split;
//   ibv[b][n][p] = bf16(inv)  (COALESCED; transposed later by k_tr);
//   bias = log(pi) - 0.5*sum(mu^2*inv) - 0.5*sum(log(bv))
// ---------------------------------------------------------------------------
__global__ __launch_bounds__(256) void k_precompute(
    const float* __restrict__ mu, const float* __restrict__ logvar,
    const float* __restrict__ pi, u16* __restrict__ mobv_hi,
    u16* __restrict__ mobv_lo, u16* __restrict__ ibv,
    float* __restrict__ bias) {
  const int bn = blockIdx.x;          // 0 .. B_*NL-1
  const int t = threadIdx.x;
  const size_t base = (size_t)bn * P_;
  float t2 = 0.f, t3 = 0.f;
#pragma unroll
  for (int i = 0; i < P_ / 256; ++i) {
    const int p = t + i * 256;
    const float lv  = logvar[base + p];
    const float v   = expf(lv);
    const float bv  = v + 8.0f;
    const float inv = 1.0f / bv;
    const float m   = mu[base + p];
    const float x   = m * inv;
    const unsigned bits = __float_as_uint(x);
    mobv_hi[base + p] = (u16)(bits >> 16);
    const float r = x - __uint_as_float(bits & 0xFFFF0000u);
    mobv_lo[base + p] = (u16)(__float_as_uint(r) >> 16);
    ibv[base + p] = f2bf_rne(inv);   // coalesced (was 1KB-stride scatter)
    t2 += m * x;
    t3 += logf(bv);
  }
  __shared__ float r2[256];
  __shared__ float r3[256];
  r2[t] = t2; r3[t] = t3;
  __syncthreads();
  for (int s = 128; s > 0; s >>= 1) {
    if (t < s) { r2[t] += r2[t + s]; r3[t] += r3[t + s]; }
    __syncthreads();
  }
  if (t == 0) {
    const float pv = pi[bn];
    float bb;
    if (pv <= 0.f) bb = -INFINITY;
    else bb = logf(fmaxf(pv, 1.17549435e-38f)) - 0.5f * r2[0] - 0.5f * r3[0];
    bias[bn] = bb;
  }
}

// ---------------------------------------------------------------------------
// Kernel TR: ibvT[b][p][n] = ibv[b][n][p], 64x64 LDS tiles.
// ---------------------------------------------------------------------------
__global__ __launch_bounds__(256) void k_tr(const u16* __restrict__ ibv,
                                            u16* __restrict__ ibvT) {
  const int b  = blockIdx.z;
  const int p0 = blockIdx.x * 64;
  const int n0 = blockIdx.y * 64;
  const int t  = threadIdx.x;
  __shared__ u16 T[64][65];
  // load 64n x 64p tile, coalesced along p
  {
    const int ln = t >> 2, lp = (t & 3) * 16;
    const u16* src = ibv + ((size_t)b * NL + n0 + ln) * P_ + p0 + lp;
    const ushort8 v0 = *(const ushort8*)(src);
    const ushort8 v1 = *(const ushort8*)(src + 8);
#pragma unroll
    for (int j = 0; j < 8; ++j) { T[ln][lp + j] = v0[j]; T[ln][lp + 8 + j] = v1[j]; }
  }
  __syncthreads();
  // write 64p x 64n, coalesced along n
  {
    const int lp = t >> 2, ln = (t & 3) * 16;
    u16* dst = ibvT + ((size_t)b * P_ + p0 + lp) * NL + n0 + ln;
    ushort8 o0, o1;
#pragma unroll
    for (int j = 0; j < 8; ++j) { o0[j] = T[ln + j][lp]; o1[j] = T[ln + 8 + j][lp]; }
    *(ushort8*)(dst)     = o0;
    *(ushort8*)(dst + 8) = o1;
  }
}

// ---------------------------------------------------------------------------
// wv fp32 -> bf16 copy
// ---------------------------------------------------------------------------
__global__ __launch_bounds__(256) void k_wvcast(const float* __restrict__ wv,
                                                u16* __restrict__ wvb) {
  const int i = (blockIdx.x * 256 + threadIdx.x) * 4;
  const float4 f = *(const float4*)&wv[i];
  wvb[i + 0] = f2bf_rne(f.x);
  wvb[i + 1] = f2bf_rne(f.y);
  wvb[i + 2] = f2bf_rne(f.z);
  wvb[i + 3] = f2bf_rne(f.w);
}

// ---------------------------------------------------------------------------
// Kernel W (MFMA): W2pT[b][he][n] = bf16(8*sum_p mobv[n][p]*wv[he][p] + bv[he][n])
// M=512(n) x N=1024(he) x K=1024. Tile 64x128xBK32; 4 waves 2x2 (wave 32x64).
// ---------------------------------------------------------------------------
__global__ __launch_bounds__(256) void k_w2p(
    const u16* __restrict__ mobv_hi, const u16* __restrict__ mobv_lo,
    const u16* __restrict__ wvb, const float* __restrict__ bv_,
    u16* __restrict__ W2pT) {
  const int b    = blockIdx.z;
  const int row0 = blockIdx.x * 64;    // n
  const int col0 = blockIdx.y * 128;   // he
  const int t = threadIdx.x;
  const int wave = t >> 6, lane = t & 63;
  const int l16 = lane & 15, sel = lane >> 4;
  const int mrow = (wave >> 1) * 32, ncol = (wave & 1) * 64;

  __shared__ u16 Ah[64 * 32];    // 4KB
  __shared__ u16 Al[64 * 32];    // 4KB
  __shared__ u16 Bs[128 * 32];   // 8KB

  const u16* Abh = mobv_hi + ((size_t)b * NL + row0) * P_;
  const u16* Abl = mobv_lo + ((size_t)b * NL + row0) * P_;
  const u16* Bb  = wvb + (size_t)col0 * P_;

  f32x4 acc[2][4];
#pragma unroll
  for (int i = 0; i < 2; ++i)
#pragma unroll
    for (int j = 0; j < 4; ++j) acc[i][j] = (f32x4){0.f, 0.f, 0.f, 0.f};

  for (int k0 = 0; k0 < P_; k0 += 32) {
    {  // A tiles: 256 chunks each
      const int c = t;
      const int row = c >> 2, k8 = (c & 3) ^ ((row >> 1) & 3);
      gl_lds16(Abh + (size_t)row * P_ + k0 + k8 * 8, &Ah[wave * 64 * 8]);
      gl_lds16(Abl + (size_t)row * P_ + k0 + k8 * 8, &Al[wave * 64 * 8]);
    }
#pragma unroll
    for (int i = 0; i < 2; ++i) {  // B tile: 512 chunks
      const int c = t + i * 256;
      const int row = c >> 2, k8 = (c & 3) ^ ((row >> 1) & 3);
      gl_lds16(Bb + (size_t)row * P_ + k0 + k8 * 8,
               &Bs[(i * 256 + wave * 64) * 8]);
    }
    __syncthreads();
    short8 ah[2], al[2], bf[4];
#pragma unroll
    for (int mt = 0; mt < 2; ++mt) {
      const int r = mrow + mt * 16 + l16;
      const int ch = sel ^ ((r >> 1) & 3);
      ah[mt] = *(const short8*)&Ah[r * 32 + ch * 8];
      al[mt] = *(const short8*)&Al[r * 32 + ch * 8];
    }
#pragma unroll
    for (int nt = 0; nt < 4; ++nt) {
      const int r = ncol + nt * 16 + l16;
      const int ch = sel ^ ((r >> 1) & 3);
      bf[nt] = *(const short8*)&Bs[r * 32 + ch * 8];
    }
#pragma unroll
    for (int mt = 0; mt < 2; ++mt)
#pragma unroll
      for (int nt = 0; nt < 4; ++nt) {
        acc[mt][nt] = MFMA(ah[mt], bf[nt], acc[mt][nt]);
        acc[mt][nt] = MFMA(al[mt], bf[nt], acc[mt][nt]);
      }
    __syncthreads();
  }
#pragma unroll
  for (int mt = 0; mt < 2; ++mt) {
    const int nbase = row0 + mrow + mt * 16 + sel * 4;
#pragma unroll
    for (int nt = 0; nt < 4; ++nt) {
      const int he = col0 + ncol + nt * 16 + l16;
      const float4 bvv = *(const float4*)&bv_[(size_t)he * NL + nbase];
      ushort4 o;
      o.x = f2bf_rne(8.0f * acc[mt][nt][0] + bvv.x);
      o.y = f2bf_rne(8.0f * acc[mt][nt][1] + bvv.y);
      o.z = f2bf_rne(8.0f * acc[mt][nt][2] + bvv.z);
      o.w = f2bf_rne(8.0f * acc[mt][nt][3] + bvv.w);
      *(ushort4*)&W2pT[((size_t)b * HE + he) * NL + nbase] = o;
    }
  }
}

// ---------------------------------------------------------------------------
// Kernel S (MFMA): scores = U @ mobv^T, 3-term split-bf16. 128x128xBK32, dbuf.
// Wave remap 4x1: wave owns rows wave*32..+31 x ALL 128 cols -> no two waves
// share A-rows -> in-loop fp32->bf16 hi/lo split work halves (16 elem/thread
// instead of 32). B fragments 4x-shared but those are VALU-free ds_reads.
// MFMA count & order per acc unchanged -> bit-identical results.
// ---------------------------------------------------------------------------
__global__ __launch_bounds__(256) void k_scores(
    const float* __restrict__ U, const u16* __restrict__ mobv_hi,
    const u16* __restrict__ mobv_lo, const float* __restrict__ pb,
    const float* __restrict__ bias, const uint8_t* __restrict__ mask,
    float* __restrict__ attn) {
  const int b    = blockIdx.z;
  const int row0 = blockIdx.x * 128;  // gr within b
  const int col0 = blockIdx.y * 128;  // n
  const int t = threadIdx.x;
  const int wave = t >> 6, lane = t & 63;
  const int l16 = lane & 15, sel = lane >> 4;
  const int mrow = wave * 32;         // 4x1 wave map

  __shared__ float Af[2][128 * 32];  // 32KB
  __shared__ u16   Bh[2][128 * 32];  // 16KB
  __shared__ u16   Bl[2][128 * 32];  // 16KB

  const float* Ab  = U + ((size_t)b * 8192 + row0) * P_;
  const u16*   Bbh = mobv_hi + ((size_t)b * NL + col0) * P_;
  const u16*   Bbl = mobv_lo + ((size_t)b * NL + col0) * P_;

  f32x4 acc[2][8];
#pragma unroll
  for (int i = 0; i < 2; ++i)
#pragma unroll
    for (int j = 0; j < 8; ++j) acc[i][j] = (f32x4){0.f, 0.f, 0.f, 0.f};

  auto stage = [&](int buf, int k0) {
#pragma unroll
    for (int i = 0; i < 4; ++i) {
      const int c = t + i * 256;
      const int row = c >> 3, k4 = (c & 7) ^ (row & 7);
      gl_lds16(Ab + (size_t)row * P_ + k0 + k4 * 4,
               &Af[buf][(i * 256 + wave * 64) * 4]);
    }
#pragma unroll
    for (int i = 0; i < 2; ++i) {
      const int c = t + i * 256;
      const int row = c >> 2, k8 = (c & 3) ^ ((row >> 1) & 3);
      gl_lds16(Bbh + (size_t)row * P_ + k0 + k8 * 8,
               &Bh[buf][(i * 256 + wave * 64) * 8]);
      gl_lds16(Bbl + (size_t)row * P_ + k0 + k8 * 8,
               &Bl[buf][(i * 256 + wave * 64) * 8]);
    }
  };

  stage(0, 0);
  __syncthreads();
  int cur = 0;
  for (int k0 = 0; k0 < P_; k0 += 32) {
    if (k0 + 32 < P_) stage(cur ^ 1, k0 + 32);

    short8 ah[2], al[2], bh[8], bl[8];
#pragma unroll
    for (int mt = 0; mt < 2; ++mt) {
      const int r = mrow + mt * 16 + l16;
      const int c0 = (sel * 2) ^ (r & 7);
      const int c1 = (sel * 2 + 1) ^ (r & 7);
      const float4 f0 = *(const float4*)&Af[cur][r * 32 + c0 * 4];
      const float4 f1 = *(const float4*)&Af[cur][r * 32 + c1 * 4];
      const float fv[8] = {f0.x, f0.y, f0.z, f0.w, f1.x, f1.y, f1.z, f1.w};
#pragma unroll
      for (int j = 0; j < 8; ++j) {
        const unsigned bits = __float_as_uint(fv[j]);
        ah[mt][j] = (short)(bits >> 16);
        const float rr = fv[j] - __uint_as_float(bits & 0xFFFF0000u);
        al[mt][j] = (short)(__float_as_uint(rr) >> 16);
      }
    }
#pragma unroll
    for (int nt = 0; nt < 8; ++nt) {
      const int r = nt * 16 + l16;
      const int ch = sel ^ ((r >> 1) & 3);
      bh[nt] = *(const short8*)&Bh[cur][r * 32 + ch * 8];
      bl[nt] = *(const short8*)&Bl[cur][r * 32 + ch * 8];
    }
#pragma unroll
    for (int mt = 0; mt < 2; ++mt)
#pragma unroll
      for (int nt = 0; nt < 8; ++nt) {
        acc[mt][nt] = MFMA(ah[mt], bh[nt], acc[mt][nt]);
        acc[mt][nt] = MFMA(ah[mt], bl[nt], acc[mt][nt]);
        acc[mt][nt] = MFMA(al[mt], bh[nt], acc[mt][nt]);
      }
    __syncthreads();
    cur ^= 1;
  }

  const int bh_ = b * H_ + (row0 >> 9);
  float pbv[2][4];
#pragma unroll
  for (int mt = 0; mt < 2; ++mt)
#pragma unroll
    for (int r = 0; r < 4; ++r)
      pbv[mt][r] = pb[(size_t)b * 8192 + row0 + mrow + mt * 16 + sel * 4 + r];
#pragma unroll
  for (int nt = 0; nt < 8; ++nt) {
    const int n = col0 + nt * 16 + l16;
    const float bcol = bias[b * NL + n];
    const bool mk = mask[(size_t)bh_ * NL + n] != 0;
#pragma unroll
    for (int mt = 0; mt < 2; ++mt) {
#pragma unroll
      for (int r = 0; r < 4; ++r) {
        const int row = row0 + mrow + mt * 16 + sel * 4 + r;
        float s = acc[mt][nt][r] + pbv[mt][r] + bcol;
        if (mk) s = -INFINITY;
        attn[((size_t)b * 8192 + row) * NL + n] = s;
      }
    }
  }
}

// ---------------------------------------------------------------------------
// Kernel SM: softmax over last dim (512), wave-per-row, barrier-free.
// Also emits bf16 copy.
// ---------------------------------------------------------------------------
__global__ __launch_bounds__(256) void k_softmax(float* __restrict__ attn,
                                                 u16* __restrict__ attn_bf) {
  const int t = threadIdx.x;
  const int wave = t >> 6, lane = t & 63;
  const size_t r = (size_t)blockIdx.x * 4 + wave;
  float* row = attn + r * NL;
  const float4 v0 = ((const float4*)row)[lane * 2];
  const float4 v1 = ((const float4*)row)[lane * 2 + 1];
  float m = fmaxf(fmaxf(fmaxf(v0.x, v0.y), fmaxf(v0.z, v0.w)),
                  fmaxf(fmaxf(v1.x, v1.y), fmaxf(v1.z, v1.w)));
#pragma unroll
  for (int off = 32; off > 0; off >>= 1) m = fmaxf(m, __shfl_xor(m, off, 64));
  float e[8];
  e[0] = expf(v0.x - m); e[1] = expf(v0.y - m);
  e[2] = expf(v0.z - m); e[3] = expf(v0.w - m);
  e[4] = expf(v1.x - m); e[5] = expf(v1.y - m);
  e[6] = expf(v1.z - m); e[7] = expf(v1.w - m);
  float s = ((e[0] + e[1]) + (e[2] + e[3])) + ((e[4] + e[5]) + (e[6] + e[7]));
#pragma unroll
  for (int off = 32; off > 0; off >>= 1) s += __shfl_xor(s, off, 64);
  const float inv = 1.0f / s;
  float4 o0, o1;
  o0.x = e[0] * inv; o0.y = e[1] * inv; o0.z = e[2] * inv; o0.w = e[3] * inv;
  o1.x = e[4] * inv; o1.y = e[5] * inv; o1.z = e[6] * inv; o1.w = e[7] * inv;
  ((float4*)row)[lane * 2] = o0;
  ((float4*)row)[lane * 2 + 1] = o1;
  ushort4 b0, b1;
  b0.x = f2bf_rne(o0.x); b0.y = f2bf_rne(o0.y);
  b0.z = f2bf_rne(o0.z); b0.w = f2bf_rne(o0.w);
  b1.x = f2bf_rne(o1.x); b1.y = f2bf_rne(o1.y);
  b1.z = f2bf_rne(o1.z); b1.w = f2bf_rne(o1.w);
  ((ushort4*)(attn_bf + r * NL))[lane * 2] = b0;
  ((ushort4*)(attn_bf + r * NL))[lane * 2 + 1] = b1;
}

// ---------------------------------------------------------------------------
// Kernel M (MFMA): opS[m][p] = bf16((1 - 8*s[m][p]) * U[m][p]),
//   s = attn_bf @ ibvT   (M=8192/b x N=1024(p) x K=512(n)).
// Tile 128x128xBK32; 4 waves 2x2 (wave 64x64). Single-buffer (dbuf regressed).
// ---------------------------------------------------------------------------
__global__ __launch_bounds__(256) void k_mid(
    const u16* __restrict__ attn_bf, const u16* __restrict__ ibvT,
    const float* __restrict__ U, u16* __restrict__ opS) {
  const int b    = blockIdx.z;
  const int row0 = blockIdx.x * 128;  // m within b
  const int col0 = blockIdx.y * 128;  // p
  const int t = threadIdx.x;
  const int wave = t >> 6, lane = t & 63;
  const int l16 = lane & 15, sel = lane >> 4;
  const int mrow = (wave >> 1) * 64, ncol = (wave & 1) * 64;

  __shared__ u16 As[128 * 32];  // 8KB
  __shared__ u16 Bs[128 * 32];  // 8KB

  const u16* Ab = attn_bf + ((size_t)b * 8192 + row0) * NL;
  const u16* Bb = ibvT + ((size_t)b * P_ + col0) * NL;

  f32x4 acc[4][4];
#pragma unroll
  for (int i = 0; i < 4; ++i)
#pragma unroll
    for (int j = 0; j < 4; ++j) acc[i][j] = (f32x4){0.f, 0.f, 0.f, 0.f};

  for (int k0 = 0; k0 < NL; k0 += 32) {
#pragma unroll
    for (int i = 0; i < 2; ++i) {  // 512 chunks each for A and B
      const int c = t + i * 256;
      const int row = c >> 2, k8 = (c & 3) ^ ((row >> 1) & 3);
      gl_lds16(Ab + (size_t)row * NL + k0 + k8 * 8,
               &As[(i * 256 + wave * 64) * 8]);
      gl_lds16(Bb + (size_t)row * NL + k0 + k8 * 8,
               &Bs[(i * 256 + wave * 64) * 8]);
    }
    __syncthreads();
    short8 af[4], bf[4];
#pragma unroll
    for (int mt = 0; mt < 4; ++mt) {
      const int r = mrow + mt * 16 + l16;
      const int ch = sel ^ ((r >> 1) & 3);
      af[mt] = *(const short8*)&As[r * 32 + ch * 8];
    }
#pragma unroll
    for (int nt = 0; nt < 4; ++nt) {
      const int r = ncol + nt * 16 + l16;
      const int ch = sel ^ ((r >> 1) & 3);
      bf[nt] = *(const short8*)&Bs[r * 32 + ch * 8];
    }
#pragma unroll
    for (int mt = 0; mt < 4; ++mt)
#pragma unroll
      for (int nt = 0; nt < 4; ++nt)
        acc[mt][nt] = MFMA(af[mt], bf[nt], acc[mt][nt]);
    __syncthreads();
  }

#pragma unroll
  for (int mt = 0; mt < 4; ++mt) {
#pragma unroll
    for (int r = 0; r < 4; ++r) {
      const int m = row0 + mrow + mt * 16 + sel * 4 + r;
      const float* Urow = U + ((size_t)b * 8192 + m) * P_;
      u16* orow = opS + ((size_t)b * 8192 + m) * P_;
#pragma unroll
      for (int nt = 0; nt < 4; ++nt) {
        const int p = col0 + ncol + nt * 16 + l16;
        const float u = Urow[p];
        orow[p] = f2bf_rne((1.0f - 8.0f * acc[mt][nt][r]) * u);
      }
    }
  }
}

// ---------------------------------------------------------------------------
// Kernel O2 (MFMA): out[m][e] = opS[m][:] @ wvb[he][:] + attn_bf[m][:] @ W2pT[he][:]
// Per block: 64 rows x 64 e for one bh. Tile 64x64xBK64, 4 waves 2x2 (32x32).
// ---------------------------------------------------------------------------
__global__ __launch_bounds__(256) void k_out2(
    const u16* __restrict__ opS, const u16* __restrict__ attn_bf,
    const u16* __restrict__ wvb, const u16* __restrict__ W2pT,
    float* __restrict__ out) {
  const int bh = blockIdx.y;
  const int b = bh >> 4, h = bh & 15;
  const int row0g = bh * NT + blockIdx.x * 64;  // global row in [B*H*Nt)
  const int t = threadIdx.x;
  const int wave = t >> 6, lane = t & 63;
  const int l16 = lane & 15, sel = lane >> 4;
  const int mrow = (wave >> 1) * 32, ncol = (wave & 1) * 32;

  __shared__ u16 As[64 * 64];  // 8KB
  __shared__ u16 Bs[64 * 64];  // 8KB

  f32x4 acc[2][2];
#pragma unroll
  for (int i = 0; i < 2; ++i)
#pragma unroll
    for (int j = 0; j < 2; ++j) acc[i][j] = (f32x4){0.f, 0.f, 0.f, 0.f};

  // ---- term 1: opS @ wvb^T  (K = p, 1024) ----
  const u16* Ab1 = opS + (size_t)row0g * P_;
  const u16* Bb1 = wvb + (size_t)(h * 64) * P_;
  for (int k0 = 0; k0 < P_; k0 += 64) {
#pragma unroll
    for (int i = 0; i < 2; ++i) {  // 512 chunks each
      const int c = t + i * 256;
      const int row = c >> 3, k8 = (c & 7) ^ (row & 7);
      gl_lds16(Ab1 + (size_t)row * P_ + k0 + k8 * 8,
               &As[(i * 256 + wave * 64) * 8]);
      gl_lds16(Bb1 + (size_t)row * P_ + k0 + k8 * 8,
               &Bs[(i * 256 + wave * 64) * 8]);
    }
    __syncthreads();
    short8 af[2][2], bf[2][2];
#pragma unroll
    for (int mt = 0; mt < 2; ++mt) {
      const int r = mrow + mt * 16 + l16;
#pragma unroll
      for (int kk = 0; kk < 2; ++kk) {
        const int ch = (kk * 4 + sel) ^ (r & 7);
        af[mt][kk] = *(const short8*)&As[r * 64 + ch * 8];
      }
    }
#pragma unroll
    for (int nt = 0; nt < 2; ++nt) {
      const int r = ncol + nt * 16 + l16;
#pragma unroll
      for (int kk = 0; kk < 2; ++kk) {
        const int ch = (kk * 4 + sel) ^ (r & 7);
        bf[nt][kk] = *(const short8*)&Bs[r * 64 + ch * 8];
      }
    }
#pragma unroll
    for (int mt = 0; mt < 2; ++mt)
#pragma unroll
      for (int nt = 0; nt < 2; ++nt) {
        acc[mt][nt] = MFMA(af[mt][0], bf[nt][0], acc[mt][nt]);
        acc[mt][nt] = MFMA(af[mt][1], bf[nt][1], acc[mt][nt]);
      }
    __syncthreads();
  }

  // ---- term 2: attn_bf @ W2pT^T  (K = n, 512) ----
  const u16* Ab2 = attn_bf + (size_t)row0g * NL;
  const u16* Bb2 = W2pT + ((size_t)b * HE + h * 64) * NL;
  for (int k0 = 0; k0 < NL; k0 += 64) {
#pragma unroll
    for (int i = 0; i < 2; ++i) {
      const int c = t + i * 256;
      const int row = c >> 3, k8 = (c & 7) ^ (row & 7);
      gl_lds16(Ab2 + (size_t)row * NL + k0 + k8 * 8,
               &As[(i * 256 + wave * 64) * 8]);
      gl_lds16(Bb2 + (size_t)row * NL + k0 + k8 * 8,
               &Bs[(i * 256 + wave * 64) * 8]);
    }
    __syncthreads();
    short8 af[2][2], bf[2][2];
#pragma unroll
    for (int mt = 0; mt < 2; ++mt) {
      const int r = mrow + mt * 16 + l16;
#pragma unroll
      for (int kk = 0; kk < 2; ++kk) {
        const int ch = (kk * 4 + sel) ^ (r & 7);
        af[mt][kk] = *(const short8*)&As[r * 64 + ch * 8];
      }
    }
#pragma unroll
    for (int nt = 0; nt < 2; ++nt) {
      const int r = ncol + nt * 16 + l16;
#pragma unroll
      for (int kk = 0; kk < 2; ++kk) {
        const int ch = (kk * 4 + sel) ^ (r & 7);
        bf[nt][kk] = *(const short8*)&Bs[r * 64 + ch * 8];
      }
    }
#pragma unroll
    for (int mt = 0; mt < 2; ++mt)
#pragma unroll
      for (int nt = 0; nt < 2; ++nt) {
        acc[mt][nt] = MFMA(af[mt][0], bf[nt][0], acc[mt][nt]);
        acc[mt][nt] = MFMA(af[mt][1], bf[nt][1], acc[mt][nt]);
      }
    __syncthreads();
  }

#pragma unroll
  for (int mt = 0; mt < 2; ++mt)
#pragma unroll
    for (int nt = 0; nt < 2; ++nt)
#pragma unroll
      for (int r = 0; r < 4; ++r) {
        const int row = row0g + mrow + mt * 16 + sel * 4 + r;
        const int e = ncol + nt * 16 + l16;
        out[(size_t)row * E_ + e] = acc[mt][nt][r];
      }
}

// ---------------------------------------------------------------------------
extern "C" void kernel_launch(void* const* d_in, const int* in_sizes, int n_in,
                              void* d_out, int out_size, void* d_ws, size_t ws_size,
                              hipStream_t stream) {
  const float*   u    = (const float*)d_in[0];   // [B,H,Nt,P]
  const float*   pb   = (const float*)d_in[1];   // [B,H,Nt,1]
  const float*   mu   = (const float*)d_in[2];   // [B,Nl,P]
  const float*   logv = (const float*)d_in[3];   // [B,Nl,P]
  const float*   pi   = (const float*)d_in[4];   // [B,Nl,1]
  const float*   wv   = (const float*)d_in[5];   // [H,E,P]
  const float*   bv   = (const float*)d_in[6];   // [H,E,Nl]
  const uint8_t* mask = (const uint8_t*)d_in[7]; // [B*H,1,Nl] bool

  float* out  = (float*)d_out;                      // [B*H,Nt,E]
  float* attn = out + (size_t)BH * NT * E_;         // [B*H,Nt,Nl]

  u16*   mobv_hi = (u16*)d_ws;                              // 4 MB
  u16*   mobv_lo = mobv_hi + (size_t)B_ * NL * P_;          // 4 MB
  u16*   ibvT    = mobv_lo + (size_t)B_ * NL * P_;          // [b][p][n] 4 MB
  u16*   W2pT    = ibvT + (size_t)B_ * P_ * NL;             // [b][he][n] 4 MB
  u16*   wvb     = W2pT + (size_t)B_ * HE * NL;             // [he][p] 2 MB
  float* bias    = (float*)(wvb + (size_t)HE * P_);         // B*NL fp32 (8 KB)
  u16*   attn_bf = (u16*)(bias + (size_t)B_ * NL);          // [B*H,Nt,Nl] 32 MB
  u16*   opS     = attn_bf + (size_t)BH * NT * NL;          // [B*H,Nt,P] 64 MB
  u16*   ibv     = opS;  // alias: k_tr consumes ibv BEFORE k_mid writes opS

  k_precompute<<<B_ * NL, 256, 0, stream>>>(mu, logv, pi, mobv_hi, mobv_lo,
                                            ibv, bias);
  k_tr<<<dim3(P_ / 64, NL / 64, B_), 256, 0, stream>>>(ibv, ibvT);
  k_wvcast<<<(HE * P_) / 1024, 256, 0, stream>>>(wv, wvb);
  k_w2p<<<dim3(NL / 64, HE / 128, B_), 256, 0, stream>>>(mobv_hi, mobv_lo, wvb,
                                                         bv, W2pT);
  k_scores<<<dim3(8192 / 128, NL / 128, B_), 256, 0, stream>>>(
      u, mobv_hi, mobv_lo, pb, bias, mask, attn);
  k_softmax<<<(B_ * H_ * NT) / 4, 256, 0, stream>>>(attn, attn_bf);
  k_mid<<<dim3(8192 / 128, P_ / 128, B_), 256, 0, stream>>>(attn_bf, ibvT, u,
                                                            opS);
  k_out2<<<dim3(NT / 64, BH), 256, 0, stream>>>(opS, attn_bf, wvb, W2pT, out);
}